// Round 3
// baseline (653.302 us; speedup 1.0000x reference)
//
#include <hip/hip_runtime.h>

typedef unsigned short u16;
typedef u16    u16x4  __attribute__((ext_vector_type(4)));
typedef u16    u16x8  __attribute__((ext_vector_type(8)));
typedef __bf16 bf16x8 __attribute__((ext_vector_type(8)));
typedef float  f32x4  __attribute__((ext_vector_type(4)));

#define DEV static __device__ __forceinline__

DEV float bf2f(u16 h) {
    union { unsigned int u; float f; } c; c.u = ((unsigned int)h) << 16; return c.f;
}
DEV u16 f2bf(float f) {
    union { float f; unsigned int u; } c; c.f = f;
    unsigned int u = c.u + 0x7FFFu + ((c.u >> 16) & 1u);
    return (u16)(u >> 16);
}
DEV bf16x8 ld8(const u16* p) {
    return __builtin_bit_cast(bf16x8, *(const u16x8*)p);
}
DEV void gload_lds16(const u16* g, u16* l) {
    __builtin_amdgcn_global_load_lds((__attribute__((address_space(1))) void*)g,
                                     (__attribute__((address_space(3))) void*)l,
                                     16, 0, 0);
}
// raw barrier with compiler memory fences (no vmcnt drain, unlike __syncthreads)
DEV void bar() {
    asm volatile("" ::: "memory");
    __builtin_amdgcn_s_barrier();
    asm volatile("" ::: "memory");
}
#define VMCNT(n) asm volatile("s_waitcnt vmcnt(" #n ")" ::: "memory")

// ---------------------------------------------------------------------------
// f32 -> bf16 elementwise convert (n multiple of 4).
// ---------------------------------------------------------------------------
__global__ __launch_bounds__(256) void f32_to_bf16(
    const float* __restrict__ src, u16* __restrict__ dst, int n)
{
    int i = (blockIdx.x * 256 + threadIdx.x) * 4;
    if (i < n) {
        f32x4 v = *(const f32x4*)(src + i);
        u16x4 o;
        o[0] = f2bf(v[0]); o[1] = f2bf(v[1]); o[2] = f2bf(v[2]); o[3] = f2bf(v[3]);
        *(u16x4*)(dst + i) = o;
    }
}

// ---------------------------------------------------------------------------
// Prep: conv weights [O][I][KS] -> [O][tap][I]  (row o has K=1536 contiguous:
// tap-major within row), fold BN scale (0.125 attn scale into Q). bf16 out.
// ---------------------------------------------------------------------------
__global__ __launch_bounds__(256) void prep_weights(
    const float* __restrict__ Wq, const float* __restrict__ gq, const float* __restrict__ vq,
    const float* __restrict__ Wk, const float* __restrict__ gk, const float* __restrict__ vk,
    u16* __restrict__ Wqt, u16* __restrict__ Wkt)
{
    int idx = blockIdx.x * 256 + threadIdx.x;        // 0 .. 2*786432-1
    int mat = idx >= 786432;                         // 0=q, 1=k
    int rem = idx - mat * 786432;
    int tap = rem / 262144;
    int oi  = rem - tap * 262144;
    int o = oi >> 9, i = oi & 511;
    const float* W = mat ? Wk : Wq;
    const float* g = mat ? gk : gq;
    const float* v = mat ? vk : vq;
    float s = g[o] * rsqrtf(v[o] + 1e-5f) * (mat ? 1.0f : 0.125f);
    float w = W[(o * 512 + i) * 3 + tap] * s;
    (mat ? Wkt : Wqt)[(o * 3 + tap) * 512 + i] = f2bf(w);   // [o][1536]
}

__global__ __launch_bounds__(256) void prep_bias(
    const float* bq, const float* gq, const float* betaq, const float* mq, const float* vq,
    const float* bk, const float* gk, const float* betak, const float* mk, const float* vk,
    float* __restrict__ biasq, float* __restrict__ biask, u16* __restrict__ zb)
{
    int o = blockIdx.x * 256 + threadIdx.x;
    if (o < 512) {
        float sq = gq[o] * rsqrtf(vq[o] + 1e-5f);
        biasq[o] = ((bq[o] - mq[o]) * sq + betaq[o]) * 0.125f;
        float sk = gk[o] * rsqrtf(vk[o] + 1e-5f);
        biask[o] = (bk[o] - mk[o]) * sk + betak[o];
    }
    if (blockIdx.x == 0 && threadIdx.x < 64) zb[threadIdx.x] = 0;  // zero-pad source
}

// ---------------------------------------------------------------------------
// K1: fused QKV, 8-phase counted-vmcnt schedule. Round-3 re-tile:
// waves 2M x 4N (per-wave output 128x64) -> 24 ds_read_b128 per 64 MFMA
// per K-tile (was 36 with fully-redundant A reads) — LDS read throughput
// now ~matches MFMA demand (the round-2 bottleneck).
//
// Half-tile granularity = K-halves: Ak/Bk half = 256 rows x 32 K-cols, 16KB.
// LDS layout per matrix: [buf][ks][256][32] u16 (row stride 64B). Swizzle:
// 16B slot sl holds global K-piece sl ^ ((row>>1)&3); odd rows naturally
// shift 16 banks (64B stride) -> 8 consecutive lanes hit 8 distinct 16B
// bank-groups on frag reads (conflict-free). gload_lds dest stays linear
// (chunk c -> c*16B); global source is pre-swizzled (XOR is an involution).
//
// Phases per K-tile (ks, mh): ph0(ks0,mh0: +B[ks0]) ph1(ks0,mh1)
//                             ph2(ks1,mh0: +B[ks1]) ph3(ks1,mh1)
// Stage during tile kt (for kt+1): ph0:Ak0 ph1:Bk0 ph2:Ak1 ph3:Bk1.
// Waits: VMCNT(4) at tile boundary (Ak0,Bk0 of next landed; Ak1,Bk1 fly),
//        VMCNT(4) before ph2 (current Ak1,Bk1 landed; next Ak0,Bk0 fly).
// Final tile: VMCNT(0) before ph2 (nothing else in flight to count).
// ---------------------------------------------------------------------------
__global__ __launch_bounds__(512, 1) void qkv8(
    const u16* __restrict__ Xb,
    const u16* __restrict__ Wq3, const u16* __restrict__ Wk3, const u16* __restrict__ Wv1,
    const float* __restrict__ biasq, const float* __restrict__ biask, const float* __restrict__ bv,
    const u16* __restrict__ zbuf,
    u16* __restrict__ Qa, u16* __restrict__ Ka, u16* __restrict__ Va, int b0)
{
    __shared__ __align__(16) u16 As[2 * 16384];   // [buf][ks][256][32]
    __shared__ __align__(16) u16 Bs[2 * 16384];

    // T1: XCD-chunked bijective swizzle (total 1536 or 192, both %8==0).
    const int total = gridDim.x;
    const int cpx   = total >> 3;
    const int s     = blockIdx.x;
    const int w     = (s & 7) * cpx + (s >> 3);
    const int wc    = w % 6;                  // which*2 + cb-index (fastest)
    const int bt    = w / 6;                  // (brel, tpair)
    const int which = wc >> 1;                // 0=q 1=k 2=v
    const int cb    = (wc & 1) * 256;
    const int tpair = bt & 31;
    const int brel  = bt >> 5;
    const int b     = b0 + brel;

    const int tid  = threadIdx.x;
    const int wave = tid >> 6;
    const int lane = tid & 63;
    const int l15  = lane & 15;
    const int q4   = lane >> 4;
    const int wm   = (wave >> 2) * 128;       // 2 M-groups
    const int wn3  = (wave & 3) * 64;         // 4 N-groups

    const u16* WB = (which == 0) ? Wq3 : (which == 1) ? Wk3 : Wv1;
    const int  KW = (which == 2) ? 512 : 1536;
    const int  NT = (which == 2) ? 8 : 24;

    f32x4 acc[8][4];
#pragma unroll
    for (int a = 0; a < 8; ++a)
#pragma unroll
        for (int ni = 0; ni < 4; ++ni) acc[a][ni] = f32x4{0.f, 0.f, 0.f, 0.f};

    // stage one K-half of A (256 rows x 32 K-cols) into buf bufp, half ks
    auto stageA = [&](int kt, int bufp, int ks) {
        int tap = (which == 2) ? 0 : (kt >> 3);
        int kb  = ((which == 2) ? (kt << 6) : ((kt & 7) << 6)) + ks * 32;
#pragma unroll
        for (int j = 0; j < 2; ++j) {
            int c = j * 512 + tid;            // 0..1023
            int r = c >> 2;                   // row 0..255 (r>>7 == j)
            int ss = (c & 3) ^ ((r >> 1) & 3);
            int tsrc = 2 * tpair + j + ((which == 2) ? 0 : (tap - 2));
            const u16* src = (tsrc < 0) ? zbuf
                : Xb + ((size_t)((b * 64 + tsrc) * 128 + (r & 127))) * 512 + kb + ss * 8;
            gload_lds16(src, As + bufp * 16384 + ks * 8192 + c * 8);
        }
    };
    auto stageB = [&](int kt, int bufp, int ks) {
#pragma unroll
        for (int j = 0; j < 2; ++j) {
            int c = j * 512 + tid;
            int r = c >> 2;
            int ss = (c & 3) ^ ((r >> 1) & 3);
            const u16* src = WB + (size_t)(cb + r) * KW + (kt << 6) + ks * 32 + ss * 8;
            gload_lds16(src, Bs + bufp * 16384 + ks * 8192 + c * 8);
        }
    };

#define READ_B(ks) \
    _Pragma("unroll") \
    for (int ni = 0; ni < 4; ++ni) { \
        int rr = wn3 + ni * 16 + l15; \
        bfr[ni] = ld8(Bcur + (ks) * 8192 + rr * 32 + ((q4 ^ ((rr >> 1) & 3)) << 3)); \
    }

#define READ_A(ks, mh) \
    _Pragma("unroll") \
    for (int f = 0; f < 4; ++f) { \
        int rr = wm + (mh) * 64 + f * 16 + l15; \
        af[f] = ld8(Acur + (ks) * 8192 + rr * 32 + ((q4 ^ ((rr >> 1) & 3)) << 3)); \
    }

#define PHASE_MFMA(mh) \
    __builtin_amdgcn_s_setprio(1); \
    _Pragma("unroll") \
    for (int f = 0; f < 4; ++f) \
        _Pragma("unroll") \
        for (int ni = 0; ni < 4; ++ni) \
            acc[(mh) * 4 + f][ni] = __builtin_amdgcn_mfma_f32_16x16x32_bf16( \
                af[f], bfr[ni], acc[(mh) * 4 + f][ni], 0, 0, 0); \
    __builtin_amdgcn_s_setprio(0);

    // prologue: Ak0,Bk0 first (needed first), then Ak1,Bk1 (may stay in flight)
    stageA(0, 0, 0); stageB(0, 0, 0);
    stageA(0, 0, 1); stageB(0, 0, 1);
    VMCNT(4);
    bar();

    for (int kt = 0; kt < NT; ++kt) {
        const int cur = kt & 1, nxt = cur ^ 1;
        const bool pf = (kt + 1 < NT);
        const u16* Acur = As + cur * 16384;
        const u16* Bcur = Bs + cur * 16384;
        bf16x8 af[4], bfr[4];

        // ph0: ks0, M-half 0 (+ B[ks0] frags)
        READ_B(0);
        READ_A(0, 0);
        if (pf) stageA(kt + 1, nxt, 0);
        bar();
        PHASE_MFMA(0);
        bar();

        // ph1: ks0, M-half 1
        READ_A(0, 1);
        if (pf) stageB(kt + 1, nxt, 0);
        bar();
        PHASE_MFMA(1);
        if (pf) { VMCNT(4); } else { VMCNT(0); }   // cur Ak1,Bk1 landed
        bar();

        // ph2: ks1, M-half 0 (+ B[ks1] frags)
        READ_B(1);
        READ_A(1, 0);
        if (pf) stageA(kt + 1, nxt, 1);
        bar();
        PHASE_MFMA(0);
        bar();

        // ph3: ks1, M-half 1
        READ_A(1, 1);
        if (pf) stageB(kt + 1, nxt, 1);
        bar();
        PHASE_MFMA(1);
        if (pf) { VMCNT(4); }                      // next Ak0,Bk0 landed
        bar();
    }

#undef READ_B
#undef READ_A
#undef PHASE_MFMA

    // Epilogue: 16x16x32 C/D layout: col=lane&15, row=q4*4+reg within frag.
    const float* biasp = (which == 0) ? biasq : (which == 1) ? biask : bv;
    float bias4[4];
#pragma unroll
    for (int ni = 0; ni < 4; ++ni) bias4[ni] = biasp[cb + wn3 + ni * 16 + l15];
    u16* Outp = (which == 0) ? Qa : (which == 1) ? Ka : Va;
#pragma unroll
    for (int a = 0; a < 8; ++a) {
#pragma unroll
        for (int ni = 0; ni < 4; ++ni) {
            int c = cb + wn3 + ni * 16 + l15;
            int h = c >> 6, dd = c & 63;
#pragma unroll
            for (int r = 0; r < 4; ++r) {
                int row = wm + (a >> 2) * 64 + (a & 3) * 16 + q4 * 4 + r;  // 0..255
                int n = row & 127, tt = 2 * tpair + (row >> 7);
                float val = acc[a][ni][r] + bias4[ni];
                Outp[((((size_t)(brel * 128 + n)) * 8 + h) * 64 + tt) * 64 + dd] = f2bf(val);
            }
        }
    }
}

// ---------------------------------------------------------------------------
// K2: attention per (brel,n,h). 64x64 tiles, full softmax in regs.
// Writes output over the (dead) Q buffer in the same [brel][n][h][t][d] layout.
// (unchanged; verified)
// ---------------------------------------------------------------------------
__global__ __launch_bounds__(256) void attn_kernel(
    const u16* __restrict__ Qa, const u16* __restrict__ Ka, const u16* __restrict__ Va,
    u16* __restrict__ AO)
{
    __shared__ __align__(16) u16 Qs[64 * 72];
    __shared__ __align__(16) u16 Ks[64 * 72];
    __shared__ __align__(16) u16 Vt[64 * 72];   // transposed: [d][t]
    __shared__ __align__(16) u16 Ps[64 * 72];

    const int h = blockIdx.x, n = blockIdx.y, brel = blockIdx.z;
    const int tid = threadIdx.x, wave = tid >> 6, lane = tid & 63;
    const int l15 = lane & 15, q4 = lane >> 4;
    const size_t base = ((size_t)((brel * 128 + n) * 8 + h)) * 4096;

#pragma unroll
    for (int i = 0; i < 2; i++) {
        int chunk = i * 256 + tid;                // 0..511
        int row = chunk >> 3, kc = chunk & 7;
        u16x8 vq = *(const u16x8*)(Qa + base + chunk * 8);
        u16x8 vk = *(const u16x8*)(Ka + base + chunk * 8);
        u16x8 vv = *(const u16x8*)(Va + base + chunk * 8);
        *(u16x8*)(Qs + row * 72 + kc * 8) = vq;
        *(u16x8*)(Ks + row * 72 + kc * 8) = vk;
#pragma unroll
        for (int j = 0; j < 8; j++) Vt[(kc * 8 + j) * 72 + row] = vv[j];
    }
    __syncthreads();

    // S = Q K^T  (scale already folded into Q)
    f32x4 s[4];
#pragma unroll
    for (int ni = 0; ni < 4; ni++) s[ni] = f32x4{0.f, 0.f, 0.f, 0.f};
    bf16x8 aq[2];
#pragma unroll
    for (int ks = 0; ks < 2; ks++)
        aq[ks] = ld8(Qs + (wave * 16 + l15) * 72 + ks * 32 + q4 * 8);
#pragma unroll
    for (int ni = 0; ni < 4; ni++) {
        int p = ni * 16 + l15;
#pragma unroll
        for (int ks = 0; ks < 2; ks++) {
            bf16x8 bk8 = ld8(Ks + p * 72 + ks * 32 + q4 * 8);
            s[ni] = __builtin_amdgcn_mfma_f32_16x16x32_bf16(aq[ks], bk8, s[ni], 0, 0, 0);
        }
    }

    // row softmax
    float rmax[4], rsum[4], inv[4];
#pragma unroll
    for (int r = 0; r < 4; r++)
        rmax[r] = fmaxf(fmaxf(s[0][r], s[1][r]), fmaxf(s[2][r], s[3][r]));
#pragma unroll
    for (int m = 1; m < 16; m <<= 1)
#pragma unroll
        for (int r = 0; r < 4; r++)
            rmax[r] = fmaxf(rmax[r], __shfl_xor(rmax[r], m, 64));
    float e[4][4];
#pragma unroll
    for (int r = 0; r < 4; r++) rsum[r] = 0.f;
#pragma unroll
    for (int ni = 0; ni < 4; ni++)
#pragma unroll
        for (int r = 0; r < 4; r++) {
            e[ni][r] = __expf(s[ni][r] - rmax[r]);
            rsum[r] += e[ni][r];
        }
#pragma unroll
    for (int m = 1; m < 16; m <<= 1)
#pragma unroll
        for (int r = 0; r < 4; r++)
            rsum[r] += __shfl_xor(rsum[r], m, 64);
#pragma unroll
    for (int r = 0; r < 4; r++) inv[r] = 1.0f / rsum[r];

    // store unnormalized P (bf16)
#pragma unroll
    for (int ni = 0; ni < 4; ni++)
#pragma unroll
        for (int r = 0; r < 4; r++)
            Ps[(wave * 16 + q4 * 4 + r) * 72 + ni * 16 + l15] = f2bf(e[ni][r]);
    __syncthreads();

    // O = P V
    f32x4 o[4];
#pragma unroll
    for (int ni = 0; ni < 4; ni++) o[ni] = f32x4{0.f, 0.f, 0.f, 0.f};
    bf16x8 ap[2];
#pragma unroll
    for (int ks = 0; ks < 2; ks++)
        ap[ks] = ld8(Ps + (wave * 16 + l15) * 72 + ks * 32 + q4 * 8);
#pragma unroll
    for (int ni = 0; ni < 4; ni++) {
        int dd = ni * 16 + l15;
#pragma unroll
        for (int ks = 0; ks < 2; ks++) {
            bf16x8 bv8 = ld8(Vt + dd * 72 + ks * 32 + q4 * 8);
            o[ni] = __builtin_amdgcn_mfma_f32_16x16x32_bf16(ap[ks], bv8, o[ni], 0, 0, 0);
        }
    }

#pragma unroll
    for (int ni = 0; ni < 4; ni++) {
        int dd = ni * 16 + l15;
#pragma unroll
        for (int r = 0; r < 4; r++) {
            int tt = wave * 16 + q4 * 4 + r;
            AO[base + tt * 64 + dd] = f2bf(o[ni][r] * inv[r]);
        }
    }
}

// ---------------------------------------------------------------------------
// K3: output projection (2-barrier BK=64 structure with T2 swizzle).
// ---------------------------------------------------------------------------
__global__ __launch_bounds__(256) void proj_gemm(
    const u16* __restrict__ AO, const u16* __restrict__ Wo, const float* __restrict__ bo,
    float* __restrict__ Out, int b0)
{
    __shared__ __align__(16) u16 As[128 * 64];
    __shared__ __align__(16) u16 Bs[128 * 64];

    const int cb   = blockIdx.x * 128;
    const int rt   = blockIdx.y;
    const int brel = rt >> 6;
    const int b    = b0 + brel;
    const int t    = rt & 63;

    const int tid  = threadIdx.x;
    const int wave = tid >> 6;
    const int lane = tid & 63;
    const int wm   = (wave & 1) * 64;
    const int wn   = (wave >> 1) * 64;
    const int l31  = lane & 31;
    const int q5   = lane >> 5;

    typedef float f32x16_t __attribute__((ext_vector_type(16)));
    f32x16_t acc[2][2];
#pragma unroll
    for (int mi = 0; mi < 2; mi++)
#pragma unroll
        for (int ni = 0; ni < 2; ni++)
#pragma unroll
            for (int e = 0; e < 16; e++) acc[mi][ni][e] = 0.f;

    for (int kk = 0; kk < 512; kk += 64) {
        __syncthreads();
#pragma unroll
        for (int i = 0; i < 4; ++i) {
            int p   = i * 256 + tid;
            int row = p >> 3;
            int sl  = (p & 7) ^ (row & 7);
            int k   = kk + sl * 8;
            int hh  = k >> 6, d0 = k & 63;
            const u16* ga = AO + ((((size_t)(brel * 128 + row)) * 8 + hh) * 64 + t) * 64 + d0;
            gload_lds16(ga, As + p * 8);
            gload_lds16(Wo + (size_t)(cb + row) * 512 + k, Bs + p * 8);
        }
        __syncthreads();

#pragma unroll
        for (int half = 0; half < 2; ++half) {
            bf16x8 af[2][2], bf[2][2];
#pragma unroll
            for (int mi = 0; mi < 2; mi++) {
                int r = wm + mi * 32 + l31;
#pragma unroll
                for (int j = 0; j < 2; j++) {
                    int k2 = half * 2 + j;
                    af[mi][j] = ld8(As + ((r * 64 + k2 * 16 + q5 * 8) ^ ((r & 7) << 3)));
                }
            }
#pragma unroll
            for (int ni = 0; ni < 2; ni++) {
                int c = wn + ni * 32 + l31;
#pragma unroll
                for (int j = 0; j < 2; j++) {
                    int k2 = half * 2 + j;
                    bf[ni][j] = ld8(Bs + ((c * 64 + k2 * 16 + q5 * 8) ^ ((c & 7) << 3)));
                }
            }
#pragma unroll
            for (int j = 0; j < 2; j++)
#pragma unroll
                for (int mi = 0; mi < 2; mi++)
#pragma unroll
                    for (int ni = 0; ni < 2; ni++)
                        acc[mi][ni] = __builtin_amdgcn_mfma_f32_32x32x16_bf16(
                            af[mi][j], bf[ni][j], acc[mi][ni], 0, 0, 0);
        }
    }

#pragma unroll
    for (int mi = 0; mi < 2; mi++) {
#pragma unroll
        for (int ni = 0; ni < 2; ni++) {
            int c = cb + wn + ni * 32 + l31;
            float bias = bo[c];
#pragma unroll
            for (int r = 0; r < 16; r++) {
                int n = wm + mi * 32 + (r & 3) + ((r >> 2) << 3) + (q5 << 2);
                float val = acc[mi][ni][r] + bias;
                size_t idx = (((size_t)(b * 64 + t)) * 128 + n) * 512 + c;
                Out[idx] = val;
            }
        }
    }
}

// ---------------------------------------------------------------------------
extern "C" void kernel_launch(void* const* d_in, const int* in_sizes, int n_in,
                              void* d_out, int out_size, void* d_ws, size_t ws_size,
                              hipStream_t stream)
{
    const float* X     = (const float*)d_in[0];
    const float* Wq    = (const float*)d_in[1];
    const float* bq    = (const float*)d_in[2];
    const float* gq    = (const float*)d_in[3];
    const float* betaq = (const float*)d_in[4];
    const float* mq    = (const float*)d_in[5];
    const float* vq    = (const float*)d_in[6];
    const float* Wk    = (const float*)d_in[7];
    const float* bk    = (const float*)d_in[8];
    const float* gk    = (const float*)d_in[9];
    const float* betak = (const float*)d_in[10];
    const float* mk    = (const float*)d_in[11];
    const float* vk    = (const float*)d_in[12];
    const float* Wv    = (const float*)d_in[13];
    const float* bv    = (const float*)d_in[14];
    const float* Wo    = (const float*)d_in[15];
    const float* bo    = (const float*)d_in[16];
    float* outp = (float*)d_out;
    u16*   ws   = (u16*)d_ws;

    const size_t XTOT   = 33554432;   // 8*64*128*512
    const size_t XSLICE = 4194304;    // per-batch elems

    const bool big = ws_size >= (size_t)206000000;

    u16 *Xb, *Qa, *Ka, *Wqt;
    if (big) {
        Xb  = ws;
        Qa  = ws + XTOT;
        Ka  = Qa + XTOT;
        Wqt = Ka + XTOT;
    } else {
        Xb  = ws;
        Qa  = ws + XSLICE;
        Ka  = Qa + XSLICE;
        Wqt = Ka + XSLICE;
    }
    u16* Wkt = Wqt + 786432;
    u16* Wvb = Wkt + 786432;
    u16* Wob = Wvb + 262144;
    float* biasq = (float*)(Wob + 262144);
    float* biask = biasq + 512;
    u16*   zbuf  = (u16*)(biask + 512);   // 64 u16 zero page

    hipLaunchKernelGGL(prep_weights, dim3(6144), dim3(256), 0, stream,
                       Wq, gq, vq, Wk, gk, vk, Wqt, Wkt);
    hipLaunchKernelGGL(prep_bias, dim3(2), dim3(256), 0, stream,
                       bq, gq, betaq, mq, vq, bk, gk, betak, mk, vk, biasq, biask, zbuf);
    hipLaunchKernelGGL(f32_to_bf16, dim3(256), dim3(256), 0, stream, Wv, Wvb, 262144);
    hipLaunchKernelGGL(f32_to_bf16, dim3(256), dim3(256), 0, stream, Wo, Wob, 262144);

    if (big) {
        u16* Va = (u16*)d_out;
        hipLaunchKernelGGL(f32_to_bf16, dim3(32768), dim3(256), 0, stream,
                           X, Xb, (int)XTOT);
        hipLaunchKernelGGL(qkv8, dim3(1536), dim3(512), 0, stream,
                           Xb, Wqt, Wkt, Wvb, biasq, biask, bv, zbuf, Qa, Ka, Va, 0);
        hipLaunchKernelGGL(attn_kernel, dim3(8, 128, 8), dim3(256), 0, stream,
                           Qa, Ka, Va, Qa);
        hipLaunchKernelGGL(proj_gemm, dim3(4, 512), dim3(256), 0, stream,
                           Qa, Wob, bo, outp, 0);
    } else {
        for (int p = 0; p < 8; ++p) {
            u16* Va = (u16*)d_out + (size_t)p * 2 * XSLICE;
            hipLaunchKernelGGL(f32_to_bf16, dim3(4096), dim3(256), 0, stream,
                               X + (size_t)p * XSLICE, Xb, (int)XSLICE);
            hipLaunchKernelGGL(qkv8, dim3(192), dim3(512), 0, stream,
                               Xb - (size_t)p * XSLICE, Wqt, Wkt, Wvb,
                               biasq, biask, bv, zbuf, Qa, Ka, Va, p);
            hipLaunchKernelGGL(attn_kernel, dim3(8, 128, 1), dim3(256), 0, stream,
                               Qa, Ka, Va, Qa);
            hipLaunchKernelGGL(proj_gemm, dim3(4, 64), dim3(256), 0, stream,
                               Qa, Wob, bo, outp, p);
        }
    }
}

// Round 5
// 631.709 us; speedup vs baseline: 1.0342x; 1.0342x over previous
//
#include <hip/hip_runtime.h>

typedef unsigned short u16;
typedef u16    u16x4  __attribute__((ext_vector_type(4)));
typedef u16    u16x8  __attribute__((ext_vector_type(8)));
typedef __bf16 bf16x8 __attribute__((ext_vector_type(8)));
typedef float  f32x4  __attribute__((ext_vector_type(4)));

#define DEV static __device__ __forceinline__

DEV float bf2f(u16 h) {
    union { unsigned int u; float f; } c; c.u = ((unsigned int)h) << 16; return c.f;
}
DEV u16 f2bf(float f) {
    union { float f; unsigned int u; } c; c.f = f;
    unsigned int u = c.u + 0x7FFFu + ((c.u >> 16) & 1u);
    return (u16)(u >> 16);
}
DEV bf16x8 ld8(const u16* p) {
    return __builtin_bit_cast(bf16x8, *(const u16x8*)p);
}
DEV void gload_lds16(const u16* g, u16* l) {
    __builtin_amdgcn_global_load_lds((__attribute__((address_space(1))) void*)g,
                                     (__attribute__((address_space(3))) void*)l,
                                     16, 0, 0);
}

// ---------------------------------------------------------------------------
// f32 -> bf16 elementwise convert (n multiple of 4).
// ---------------------------------------------------------------------------
__global__ __launch_bounds__(256) void f32_to_bf16(
    const float* __restrict__ src, u16* __restrict__ dst, int n)
{
    int i = (blockIdx.x * 256 + threadIdx.x) * 4;
    if (i < n) {
        f32x4 v = *(const f32x4*)(src + i);
        u16x4 o;
        o[0] = f2bf(v[0]); o[1] = f2bf(v[1]); o[2] = f2bf(v[2]); o[3] = f2bf(v[3]);
        *(u16x4*)(dst + i) = o;
    }
}

// ---------------------------------------------------------------------------
// Prep: conv weights [O][I][KS] -> [O][tap][I]  (row o has K=1536 contiguous,
// tap-major within row), fold BN scale (0.125 attn scale into Q). bf16 out.
// ---------------------------------------------------------------------------
__global__ __launch_bounds__(256) void prep_weights(
    const float* __restrict__ Wq, const float* __restrict__ gq, const float* __restrict__ vq,
    const float* __restrict__ Wk, const float* __restrict__ gk, const float* __restrict__ vk,
    u16* __restrict__ Wqt, u16* __restrict__ Wkt)
{
    int idx = blockIdx.x * 256 + threadIdx.x;        // 0 .. 2*786432-1
    int mat = idx >= 786432;                         // 0=q, 1=k
    int rem = idx - mat * 786432;
    int tap = rem / 262144;
    int oi  = rem - tap * 262144;
    int o = oi >> 9, i = oi & 511;
    const float* W = mat ? Wk : Wq;
    const float* g = mat ? gk : gq;
    const float* v = mat ? vk : vq;
    float s = g[o] * rsqrtf(v[o] + 1e-5f) * (mat ? 1.0f : 0.125f);
    float w = W[(o * 512 + i) * 3 + tap] * s;
    (mat ? Wkt : Wqt)[(o * 3 + tap) * 512 + i] = f2bf(w);   // [o][1536]
}

__global__ __launch_bounds__(256) void prep_bias(
    const float* bq, const float* gq, const float* betaq, const float* mq, const float* vq,
    const float* bk, const float* gk, const float* betak, const float* mk, const float* vk,
    float* __restrict__ biasq, float* __restrict__ biask, u16* __restrict__ zb)
{
    int o = blockIdx.x * 256 + threadIdx.x;
    if (o < 512) {
        float sq = gq[o] * rsqrtf(vq[o] + 1e-5f);
        biasq[o] = ((bq[o] - mq[o]) * sq + betaq[o]) * 0.125f;
        float sk = gk[o] * rsqrtf(vk[o] + 1e-5f);
        biask[o] = (bk[o] - mk[o]) * sk + betak[o];
    }
    if (blockIdx.x == 0 && threadIdx.x < 64) zb[threadIdx.x] = 0;  // zero-pad source
}

// ---------------------------------------------------------------------------
// K1: fused QKV. Round-4: back to the verified 2-barrier 128x128 / 4-wave /
// 16x16x32 structure (best measured: 278us @39.5% MfmaUtil), with its two
// counter-diagnosed defects fixed:
//  (a) 8-way LDS bank conflict (2.9e7 cyc) -> BK=64 rows (128B) + XOR swizzle
//      slot' = slot ^ (row&7): 16-lane frag reads spread over all 8 16B
//      positions -> 2-way (free). Staging pre-swizzles the GLOBAL source
//      (gload_lds dest stays linear); read applies the same XOR (involution).
//  (b) FETCH 835MB / 48% HBM: A-tile re-fetched by the 12 col-blocks of each
//      (b,t) scattered across XCDs -> T1 XCD-chunked bijective remap puts all
//      12 blocks of a (b,t) and consecutive t on ONE XCD: weights (3.6MB) +
//      ~3 X t-slices (384KB) stay L2-resident per XCD.
// Also: conv taps linearized to one K=1536 GEMM via [o][1536] weights
// (24 K-steps of 64 instead of 3 taps x 16 steps); causal t<0 K-steps load
// a zero page (block-uniform).
// Multi-block occupancy (32KB LDS, ~116 VGPR -> ~4 blocks/CU) supplies the
// TLP that hides the __syncthreads vmcnt drain (the 1-block/CU 8-phase
// variants measured SLOWER: R2 296us, R3 326us).
// Output layout: [brel][n][h][t][dh] (bf16), epilogue verbatim from R1.
// ---------------------------------------------------------------------------
__global__ __launch_bounds__(256, 4) void qkv_gemm(
    const u16* __restrict__ Xb,
    const u16* __restrict__ Wq3, const u16* __restrict__ Wk3, const u16* __restrict__ Wv1,
    const float* __restrict__ biasq, const float* __restrict__ biask, const float* __restrict__ bv,
    const u16* __restrict__ zbuf,
    u16* __restrict__ Qa, u16* __restrict__ Ka, u16* __restrict__ Va, int b0)
{
    __shared__ __align__(16) u16 As[128 * 64];
    __shared__ __align__(16) u16 Bs[128 * 64];

    // T1: XCD-chunked bijective remap (total = 12*gridDim.y, %8==0 always).
    const int total = gridDim.y * 12;
    const int hid   = blockIdx.y * 12 + blockIdx.x;
    const int w     = (hid & 7) * (total >> 3) + (hid >> 3);
    const int col   = w % 12;
    const int bt    = w / 12;
    const int which = col >> 2;                // 0=q 1=k 2=v
    const int cb    = (col & 3) * 128;
    const int t     = bt & 63;
    const int brel  = bt >> 6;
    const int b     = b0 + brel;

    const int tid  = threadIdx.x;
    const int wave = tid >> 6;
    const int lane = tid & 63;
    const int wm   = (wave & 1) * 64;
    const int wn   = (wave >> 1) * 64;
    const int l15  = lane & 15;
    const int q4   = lane >> 4;

    f32x4 acc[4][4];
#pragma unroll
    for (int i = 0; i < 4; i++)
#pragma unroll
        for (int j = 0; j < 4; j++) acc[i][j] = f32x4{0.f, 0.f, 0.f, 0.f};

    const u16* WB = (which == 0) ? Wq3 : (which == 1) ? Wk3 : Wv1;
    const int  KW = (which == 2) ? 512 : 1536;
    const int  NT = (which == 2) ? 8 : 24;

    for (int kt = 0; kt < NT; ++kt) {
        const int kwo = kt << 6;               // K offset in the 1536/512 row
        const int tap = kwo >> 9;              // 0 for V (kwo<512)
        const int ko  = kwo & 511;             // offset within tap's X slice
        const int tsrc = (which == 2) ? t : (t + tap - 2);
        const u16* Abase = (tsrc < 0) ? nullptr
            : Xb + ((size_t)((b * 64 + tsrc) * 128)) * 512 + ko;

        __syncthreads();
#pragma unroll
        for (int i = 0; i < 4; ++i) {
            int c   = i * 256 + tid;           // 0..1023 chunks of 16B
            int row = c >> 3;
            int sl  = c & 7;
            int ss  = sl ^ (row & 7);          // pre-swizzled global slot
            const u16* sa = Abase ? Abase + (size_t)row * 512 + ss * 8 : zbuf;
            gload_lds16(sa, As + c * 8);
            gload_lds16(WB + (size_t)(cb + row) * KW + kwo + ss * 8, Bs + c * 8);
        }
        __syncthreads();

#pragma unroll
        for (int ks = 0; ks < 2; ++ks) {
            bf16x8 af[4], bf[4];
#pragma unroll
            for (int mi = 0; mi < 4; mi++) {
                int r = wm + mi * 16 + l15;
                af[mi] = ld8(As + ((r * 64 + ks * 32 + q4 * 8) ^ ((r & 7) << 3)));
            }
#pragma unroll
            for (int ni = 0; ni < 4; ni++) {
                int cc = wn + ni * 16 + l15;
                bf[ni] = ld8(Bs + ((cc * 64 + ks * 32 + q4 * 8) ^ ((cc & 7) << 3)));
            }
#pragma unroll
            for (int mi = 0; mi < 4; mi++)
#pragma unroll
                for (int ni = 0; ni < 4; ni++)
                    acc[mi][ni] = __builtin_amdgcn_mfma_f32_16x16x32_bf16(
                        af[mi], bf[ni], acc[mi][ni], 0, 0, 0);
        }
    }

    // Epilogue (verbatim-verified): C/D 16x16 layout col=lane&15, row=q4*4+r.
    float bias[4];
#pragma unroll
    for (int ni = 0; ni < 4; ni++) {
        int c = cb + wn + ni * 16 + l15;
        bias[ni] = (which == 0) ? biasq[c] : (which == 1) ? biask[c] : bv[c];
    }
    u16* Outp = (which == 0) ? Qa : (which == 1) ? Ka : Va;
#pragma unroll
    for (int mi = 0; mi < 4; mi++) {
#pragma unroll
        for (int ni = 0; ni < 4; ni++) {
            int c = cb + wn + ni * 16 + l15;
            int h = c >> 6, dd = c & 63;
#pragma unroll
            for (int r = 0; r < 4; r++) {
                int n = wm + mi * 16 + q4 * 4 + r;
                float val = acc[mi][ni][r] + bias[ni];
                size_t idx = ((((size_t)(brel * 128 + n)) * 8 + h) * 64 + t) * 64 + dd;
                Outp[idx] = f2bf(val);
            }
        }
    }
}

// ---------------------------------------------------------------------------
// K2: attention per (brel,n,h). 64x64 tiles, full softmax in regs.
// Writes output over the (dead) Q buffer in the same [brel][n][h][t][d] layout.
// (unchanged; verified)
// ---------------------------------------------------------------------------
__global__ __launch_bounds__(256) void attn_kernel(
    const u16* __restrict__ Qa, const u16* __restrict__ Ka, const u16* __restrict__ Va,
    u16* __restrict__ AO)
{
    __shared__ __align__(16) u16 Qs[64 * 72];
    __shared__ __align__(16) u16 Ks[64 * 72];
    __shared__ __align__(16) u16 Vt[64 * 72];   // transposed: [d][t]
    __shared__ __align__(16) u16 Ps[64 * 72];

    const int h = blockIdx.x, n = blockIdx.y, brel = blockIdx.z;
    const int tid = threadIdx.x, wave = tid >> 6, lane = tid & 63;
    const int l15 = lane & 15, q4 = lane >> 4;
    const size_t base = ((size_t)((brel * 128 + n) * 8 + h)) * 4096;

#pragma unroll
    for (int i = 0; i < 2; i++) {
        int chunk = i * 256 + tid;                // 0..511
        int row = chunk >> 3, kc = chunk & 7;
        u16x8 vq = *(const u16x8*)(Qa + base + chunk * 8);
        u16x8 vk = *(const u16x8*)(Ka + base + chunk * 8);
        u16x8 vv = *(const u16x8*)(Va + base + chunk * 8);
        *(u16x8*)(Qs + row * 72 + kc * 8) = vq;
        *(u16x8*)(Ks + row * 72 + kc * 8) = vk;
#pragma unroll
        for (int j = 0; j < 8; j++) Vt[(kc * 8 + j) * 72 + row] = vv[j];
    }
    __syncthreads();

    // S = Q K^T  (scale already folded into Q)
    f32x4 s[4];
#pragma unroll
    for (int ni = 0; ni < 4; ni++) s[ni] = f32x4{0.f, 0.f, 0.f, 0.f};
    bf16x8 aq[2];
#pragma unroll
    for (int ks = 0; ks < 2; ks++)
        aq[ks] = ld8(Qs + (wave * 16 + l15) * 72 + ks * 32 + q4 * 8);
#pragma unroll
    for (int ni = 0; ni < 4; ni++) {
        int p = ni * 16 + l15;
#pragma unroll
        for (int ks = 0; ks < 2; ks++) {
            bf16x8 bk8 = ld8(Ks + p * 72 + ks * 32 + q4 * 8);
            s[ni] = __builtin_amdgcn_mfma_f32_16x16x32_bf16(aq[ks], bk8, s[ni], 0, 0, 0);
        }
    }

    // row softmax
    float rmax[4], rsum[4], inv[4];
#pragma unroll
    for (int r = 0; r < 4; r++)
        rmax[r] = fmaxf(fmaxf(s[0][r], s[1][r]), fmaxf(s[2][r], s[3][r]));
#pragma unroll
    for (int m = 1; m < 16; m <<= 1)
#pragma unroll
        for (int r = 0; r < 4; r++)
            rmax[r] = fmaxf(rmax[r], __shfl_xor(rmax[r], m, 64));
    float e[4][4];
#pragma unroll
    for (int r = 0; r < 4; r++) rsum[r] = 0.f;
#pragma unroll
    for (int ni = 0; ni < 4; ni++)
#pragma unroll
        for (int r = 0; r < 4; r++) {
            e[ni][r] = __expf(s[ni][r] - rmax[r]);
            rsum[r] += e[ni][r];
        }
#pragma unroll
    for (int m = 1; m < 16; m <<= 1)
#pragma unroll
        for (int r = 0; r < 4; r++)
            rsum[r] += __shfl_xor(rsum[r], m, 64);
#pragma unroll
    for (int r = 0; r < 4; r++) inv[r] = 1.0f / rsum[r];

    // store unnormalized P (bf16)
#pragma unroll
    for (int ni = 0; ni < 4; ni++)
#pragma unroll
        for (int r = 0; r < 4; r++)
            Ps[(wave * 16 + q4 * 4 + r) * 72 + ni * 16 + l15] = f2bf(e[ni][r]);
    __syncthreads();

    // O = P V
    f32x4 o[4];
#pragma unroll
    for (int ni = 0; ni < 4; ni++) o[ni] = f32x4{0.f, 0.f, 0.f, 0.f};
    bf16x8 ap[2];
#pragma unroll
    for (int ks = 0; ks < 2; ks++)
        ap[ks] = ld8(Ps + (wave * 16 + l15) * 72 + ks * 32 + q4 * 8);
#pragma unroll
    for (int ni = 0; ni < 4; ni++) {
        int dd = ni * 16 + l15;
#pragma unroll
        for (int ks = 0; ks < 2; ks++) {
            bf16x8 bv8 = ld8(Vt + dd * 72 + ks * 32 + q4 * 8);
            o[ni] = __builtin_amdgcn_mfma_f32_16x16x32_bf16(ap[ks], bv8, o[ni], 0, 0, 0);
        }
    }

#pragma unroll
    for (int ni = 0; ni < 4; ni++) {
        int dd = ni * 16 + l15;
#pragma unroll
        for (int r = 0; r < 4; r++) {
            int tt = wave * 16 + q4 * 4 + r;
            AO[base + tt * 64 + dd] = f2bf(o[ni][r] * inv[r]);
        }
    }
}

// ---------------------------------------------------------------------------
// K3: output projection (2-barrier BK=64 / 32x32x16 / swizzle — verified in
// rounds 2-3). Round-4 adds only the T1 XCD-chunked block remap.
// ---------------------------------------------------------------------------
__global__ __launch_bounds__(256) void proj_gemm(
    const u16* __restrict__ AO, const u16* __restrict__ Wo, const float* __restrict__ bo,
    float* __restrict__ Out, int b0)
{
    __shared__ __align__(16) u16 As[128 * 64];
    __shared__ __align__(16) u16 Bs[128 * 64];

    const int total = gridDim.y * 4;
    const int hid   = blockIdx.y * 4 + blockIdx.x;
    const int w     = (hid & 7) * (total >> 3) + (hid >> 3);
    const int cb    = (w & 3) * 128;
    const int rt    = w >> 2;
    const int brel  = rt >> 6;
    const int b     = b0 + brel;
    const int t     = rt & 63;

    const int tid  = threadIdx.x;
    const int wave = tid >> 6;
    const int lane = tid & 63;
    const int wm   = (wave & 1) * 64;
    const int wn   = (wave >> 1) * 64;
    const int l31  = lane & 31;
    const int q5   = lane >> 5;

    typedef float f32x16_t __attribute__((ext_vector_type(16)));
    f32x16_t acc[2][2];
#pragma unroll
    for (int mi = 0; mi < 2; mi++)
#pragma unroll
        for (int ni = 0; ni < 2; ni++)
#pragma unroll
            for (int e = 0; e < 16; e++) acc[mi][ni][e] = 0.f;

    for (int kk = 0; kk < 512; kk += 64) {
        __syncthreads();
#pragma unroll
        for (int i = 0; i < 4; ++i) {
            int p   = i * 256 + tid;
            int row = p >> 3;
            int sl  = (p & 7) ^ (row & 7);
            int k   = kk + sl * 8;
            int hh  = k >> 6, d0 = k & 63;
            const u16* ga = AO + ((((size_t)(brel * 128 + row)) * 8 + hh) * 64 + t) * 64 + d0;
            gload_lds16(ga, As + p * 8);
            gload_lds16(Wo + (size_t)(cb + row) * 512 + k, Bs + p * 8);
        }
        __syncthreads();

#pragma unroll
        for (int half = 0; half < 2; ++half) {
            bf16x8 af[2][2], bf[2][2];
#pragma unroll
            for (int mi = 0; mi < 2; mi++) {
                int r = wm + mi * 32 + l31;
#pragma unroll
                for (int j = 0; j < 2; j++) {
                    int k2 = half * 2 + j;
                    af[mi][j] = ld8(As + ((r * 64 + k2 * 16 + q5 * 8) ^ ((r & 7) << 3)));
                }
            }
#pragma unroll
            for (int ni = 0; ni < 2; ni++) {
                int c = wn + ni * 32 + l31;
#pragma unroll
                for (int j = 0; j < 2; j++) {
                    int k2 = half * 2 + j;
                    bf[ni][j] = ld8(Bs + ((c * 64 + k2 * 16 + q5 * 8) ^ ((c & 7) << 3)));
                }
            }
#pragma unroll
            for (int j = 0; j < 2; j++)
#pragma unroll
                for (int mi = 0; mi < 2; mi++)
#pragma unroll
                    for (int ni = 0; ni < 2; ni++)
                        acc[mi][ni] = __builtin_amdgcn_mfma_f32_32x32x16_bf16(
                            af[mi][j], bf[ni][j], acc[mi][ni], 0, 0, 0);
        }
    }

#pragma unroll
    for (int mi = 0; mi < 2; mi++) {
#pragma unroll
        for (int ni = 0; ni < 2; ni++) {
            int c = cb + wn + ni * 32 + l31;
            float bias = bo[c];
#pragma unroll
            for (int r = 0; r < 16; r++) {
                int n = wm + mi * 32 + (r & 3) + ((r >> 2) << 3) + (q5 << 2);
                float val = acc[mi][ni][r] + bias;
                size_t idx = (((size_t)(b * 64 + t)) * 128 + n) * 512 + c;
                Out[idx] = val;
            }
        }
    }
}

// ---------------------------------------------------------------------------
extern "C" void kernel_launch(void* const* d_in, const int* in_sizes, int n_in,
                              void* d_out, int out_size, void* d_ws, size_t ws_size,
                              hipStream_t stream)
{
    const float* X     = (const float*)d_in[0];
    const float* Wq    = (const float*)d_in[1];
    const float* bq    = (const float*)d_in[2];
    const float* gq    = (const float*)d_in[3];
    const float* betaq = (const float*)d_in[4];
    const float* mq    = (const float*)d_in[5];
    const float* vq    = (const float*)d_in[6];
    const float* Wk    = (const float*)d_in[7];
    const float* bk    = (const float*)d_in[8];
    const float* gk    = (const float*)d_in[9];
    const float* betak = (const float*)d_in[10];
    const float* mk    = (const float*)d_in[11];
    const float* vk    = (const float*)d_in[12];
    const float* Wv    = (const float*)d_in[13];
    const float* bv    = (const float*)d_in[14];
    const float* Wo    = (const float*)d_in[15];
    const float* bo    = (const float*)d_in[16];
    float* outp = (float*)d_out;
    u16*   ws   = (u16*)d_ws;

    const size_t XTOT   = 33554432;   // 8*64*128*512
    const size_t XSLICE = 4194304;    // per-batch elems

    const bool big = ws_size >= (size_t)206000000;

    u16 *Xb, *Qa, *Ka, *Wqt;
    if (big) {
        Xb  = ws;
        Qa  = ws + XTOT;
        Ka  = Qa + XTOT;
        Wqt = Ka + XTOT;
    } else {
        Xb  = ws;
        Qa  = ws + XSLICE;
        Ka  = Qa + XSLICE;
        Wqt = Ka + XSLICE;
    }
    u16* Wkt = Wqt + 786432;
    u16* Wvb = Wkt + 786432;
    u16* Wob = Wvb + 262144;
    float* biasq = (float*)(Wob + 262144);
    float* biask = biasq + 512;
    u16*   zbuf  = (u16*)(biask + 512);   // 64 u16 zero page

    hipLaunchKernelGGL(prep_weights, dim3(6144), dim3(256), 0, stream,
                       Wq, gq, vq, Wk, gk, vk, Wqt, Wkt);
    hipLaunchKernelGGL(prep_bias, dim3(2), dim3(256), 0, stream,
                       bq, gq, betaq, mq, vq, bk, gk, betak, mk, vk, biasq, biask, zbuf);
    hipLaunchKernelGGL(f32_to_bf16, dim3(256), dim3(256), 0, stream, Wv, Wvb, 262144);
    hipLaunchKernelGGL(f32_to_bf16, dim3(256), dim3(256), 0, stream, Wo, Wob, 262144);

    if (big) {
        u16* Va = (u16*)d_out;
        hipLaunchKernelGGL(f32_to_bf16, dim3(32768), dim3(256), 0, stream,
                           X, Xb, (int)XTOT);
        hipLaunchKernelGGL(qkv_gemm, dim3(12, 512), dim3(256), 0, stream,
                           Xb, Wqt, Wkt, Wvb, biasq, biask, bv, zbuf, Qa, Ka, Va, 0);
        hipLaunchKernelGGL(attn_kernel, dim3(8, 128, 8), dim3(256), 0, stream,
                           Qa, Ka, Va, Qa);
        hipLaunchKernelGGL(proj_gemm, dim3(4, 512), dim3(256), 0, stream,
                           Qa, Wob, bo, outp, 0);
    } else {
        for (int p = 0; p < 8; ++p) {
            u16* Va = (u16*)d_out + (size_t)p * 2 * XSLICE;
            hipLaunchKernelGGL(f32_to_bf16, dim3(4096), dim3(256), 0, stream,
                               X + (size_t)p * XSLICE, Xb, (int)XSLICE);
            hipLaunchKernelGGL(qkv_gemm, dim3(12, 64), dim3(256), 0, stream,
                               Xb - (size_t)p * XSLICE, Wqt, Wkt, Wvb,
                               biasq, biask, bv, zbuf, Qa, Ka, Va, p);
            hipLaunchKernelGGL(attn_kernel, dim3(8, 128, 1), dim3(256), 0, stream,
                               Qa, Ka, Va, Qa);
            hipLaunchKernelGGL(proj_gemm, dim3(4, 64), dim3(256), 0, stream,
                               Qa, Wob, bo, outp, p);
        }
    }
}